// Round 4
// baseline (93.323 us; speedup 1.0000x reference)
//
#include <hip/hip_runtime.h>
#include <math.h>

// Problem constants (fixed by setup_inputs)
#define B 64
#define T 60
#define NA 3
#define NS 3
#define BT (B*T)
#define NB_SCAN 2048
#define NB_CORR ((BT + 255) / 256)    // 15
#define NB_ALL (NB_SCAN + NB_CORR)    // 2063
#define NT 524288                     // scan threads; NT % 5 == 3
#define N_TOTAL 6451200.0f            // 64*3*(160^2+80^2+40^2)

// float4 counts per det tensor (each a multiple of 5 float4s)
#define G4_0 6144000
#define G4_1 1536000
#define G4_2 384000
#define FLAT4 (G4_0 + G4_1 + G4_2)    // 8064000
#define K_FULL 15                     // FLAT4 / NT = 15 full strides/thread
#define REM_START (K_FULL * NT)       // 7864320; remainder = 199680 threads

__device__ __forceinline__ float softplus_f(float x) {
    // stable softplus with fast hw transcendentals; abs err < 1e-6
    float e = __expf(-fabsf(x));
    return fmaxf(x, 0.0f) + __logf(1.0f + e);
}

__device__ __forceinline__ float pick(float4 f, int ph) {
    // ph in 1..4 -> component ph-1 (caller gates ph==0)
    return (ph == 1) ? f.x : (ph == 2) ? f.y : (ph == 3) ? f.z : f.w;
}

__device__ __forceinline__ float4 load_flat(const float4* __restrict__ d0,
                                            const float4* __restrict__ d1,
                                            const float4* __restrict__ d2,
                                            int idx) {
    // Branch is wave-uniform except at the two tensor boundaries.
    if (idx < G4_0) return d0[idx];
    if (idx < G4_0 + G4_1) return d1[idx - G4_0];
    return d2[idx - (G4_0 + G4_1)];
}

__device__ __forceinline__ float block_reduce_sum(float v) {
    for (int o = 32; o > 0; o >>= 1) v += __shfl_down(v, o, 64);
    __shared__ float s[4];
    int lane = threadIdx.x & 63;
    int w = threadIdx.x >> 6;
    if (lane == 0) s[w] = v;
    __syncthreads();
    if (threadIdx.x == 0) {
        float t = 0.0f;
        #pragma unroll
        for (int i = 0; i < 4; ++i) t += s[i];
        return t;
    }
    return 0.0f;
}

// ---------------------------------------------------------------------------
// Single kernel. Block roles:
//   blockIdx <  2048: streaming softplus sum over the flattened det space
//   blockIdx >= 2048: sparse correction, delta = -y*x - 0.5*y*softplus(-x)
// Last block to finish reduces all partials -> out (deterministic order).
// ---------------------------------------------------------------------------
__global__ void __launch_bounds__(256, 8) fused_main_kernel(
    const float* __restrict__ d0f, const float* __restrict__ d1f,
    const float* __restrict__ d2f, const float* __restrict__ anchors,
    const float* __restrict__ targets, float* __restrict__ partials,
    unsigned* __restrict__ ticket, float* __restrict__ out) {
    const float4* d0 = (const float4*)d0f;
    const float4* d1 = (const float4*)d1f;
    const float4* d2 = (const float4*)d2f;
    float acc = 0.0f;

    if (blockIdx.x < NB_SCAN) {
        int g0 = blockIdx.x * 256 + threadIdx.x;
        // Phase pattern for strides k=0..4 repeats every 5 strides
        // (5*NT ≡ 0 mod 5). NT ≡ 3 (mod 5).
        int p0 = g0 % 5;
        int p1 = p0 + 3; if (p1 >= 5) p1 -= 5;
        int p2 = p1 + 3; if (p2 >= 5) p2 -= 5;
        int p3 = p2 + 3; if (p3 >= 5) p3 -= 5;
        int p4 = p3 + 3; if (p4 >= 5) p4 -= 5;
        #pragma unroll
        for (int grp = 0; grp < 3; ++grp) {
            int base = g0 + grp * 5 * NT;
            float4 f0 = load_flat(d0, d1, d2, base);
            float4 f1 = load_flat(d0, d1, d2, base + NT);
            float4 f2 = load_flat(d0, d1, d2, base + 2 * NT);
            float4 f3 = load_flat(d0, d1, d2, base + 3 * NT);
            float4 f4 = load_flat(d0, d1, d2, base + 4 * NT);
            if (p0) acc += softplus_f(pick(f0, p0));
            if (p1) acc += softplus_f(pick(f1, p1));
            if (p2) acc += softplus_f(pick(f2, p2));
            if (p3) acc += softplus_f(pick(f3, p3));
            if (p4) acc += softplus_f(pick(f4, p4));
        }
        if (g0 < FLAT4 - REM_START) {        // 16th stride, phase == p0
            float4 f = load_flat(d0, d1, d2, g0 + REM_START);
            if (p0) acc += softplus_f(pick(f, p0));
        }
    } else {
        int tid = (blockIdx.x - NB_SCAN) * 256 + threadIdx.x;
        if (tid < BT) {
            int bi = tid / T;
            const float* tg = targets + tid * 4;
            float tx = tg[0], ty = tg[1], tw = tg[2], th = tg[3];
            bool mask = (tx != -1.0f) && (ty != -1.0f) &&
                        (tw != -1.0f) && (th != -1.0f);
            const int dims[NS] = {160, 80, 40};
            const float* dets[NS] = {d0f, d1f, d2f};

            float ov[NS][NA];
            float mx = -INFINITY;
            #pragma unroll
            for (int si = 0; si < NS; ++si) {
                float D = (float)dims[si];     // H == W at every scale
                float ztx = tx * D, zty = ty * D, ztw = tw * D, zth = th * D;
                float fx = ztx - (floorf(ztx) + 0.5f);
                float fy = zty - (floorf(zty) + 0.5f);
                float tarea = (ztw - fx) * (zth - fy);  // reference's exact expr
                #pragma unroll
                for (int ai = 0; ai < NA; ++ai) {
                    float a0 = anchors[(si * NA + ai) * 2 + 0];
                    float a1 = anchors[(si * NA + ai) * 2 + 1];
                    float lb0 = fmaxf(-0.5f * a0, fx - 0.5f * ztw);
                    float ub0 = fminf( 0.5f * a0, fx + 0.5f * ztw);
                    float lb1 = fmaxf(-0.5f * a1, fy - 0.5f * zth);
                    float ub1 = fminf( 0.5f * a1, fy + 0.5f * zth);
                    float m = ((lb0 < ub0) && (lb1 < ub1)) ? 1.0f : 0.0f;
                    float inter = (ub0 - lb0) * (ub1 - lb1) * m;
                    float v = inter / (a0 * a1 + tarea - inter);
                    ov[si][ai] = v;
                    mx = fmaxf(mx, v);
                }
            }
            if (mask) {
                #pragma unroll
                for (int si = 0; si < NS; ++si) {
                    int D = dims[si];
                    int cy = (int)(ty * (float)D);
                    int cx = (int)(tx * (float)D);
                    if (cy >= 0 && cy < D && cx >= 0 && cx < D) {
                        #pragma unroll
                        for (int ai = 0; ai < NA; ++ai) {
                            float v = ov[si][ai];
                            float y = (v == mx) ? 1.0f
                                    : ((v < 0.5f) ? 0.0f : -1.0f);
                            if (y != 0.0f) {
                                long idx = ((((long)bi * NA + ai) * D + cy) * D + cx) * 5 + 4;
                                float x = dets[si][idx];
                                acc += -y * x - 0.5f * y * softplus_f(-x);
                            }
                        }
                    }
                }
            }
        }
    }

    float bs = block_reduce_sum(acc);

    // Last-block-done final reduce (deterministic order).
    __shared__ bool is_last;
    if (threadIdx.x == 0) {
        partials[blockIdx.x] = bs;
        __threadfence();                      // make partial visible device-wide
        unsigned t = atomicAdd(ticket, 1u);
        is_last = (t == NB_ALL - 1);
    }
    __syncthreads();
    if (is_last) {
        __threadfence();                      // acquire: see all partials
        float a2 = 0.0f;
        for (int i = threadIdx.x; i < NB_ALL; i += 256)
            a2 += ((volatile float*)partials)[i];
        float tot = block_reduce_sum(a2);
        if (threadIdx.x == 0) out[0] = tot / N_TOTAL;
    }
}

extern "C" void kernel_launch(void* const* d_in, const int* in_sizes, int n_in,
                              void* d_out, int out_size, void* d_ws, size_t ws_size,
                              hipStream_t stream) {
    const float* det0    = (const float*)d_in[0];
    const float* det1    = (const float*)d_in[1];
    const float* det2    = (const float*)d_in[2];
    const float* anchors = (const float*)d_in[3];
    const float* targets = (const float*)d_in[4];
    float* out = (float*)d_out;
    float* wsf = (float*)d_ws;                    // [0,2063): partials
    unsigned* ticket = (unsigned*)(wsf + NB_ALL); // 1 x u32 ticket counter

    hipMemsetAsync(ticket, 0, sizeof(unsigned), stream);
    fused_main_kernel<<<NB_ALL, 256, 0, stream>>>(det0, det1, det2,
                                                  anchors, targets,
                                                  wsf, ticket, out);
}

// Round 5
// 30.846 us; speedup vs baseline: 3.0255x; 3.0255x over previous
//
#include <hip/hip_runtime.h>
#include <math.h>

// Problem constants (fixed by setup_inputs)
#define B 64
#define T 60
#define NA 3
#define NS 3
#define BT (B*T)

// Scan partition: blocks proportional to tensor sizes (16:4:1), so every
// thread does EXACTLY 15 grid-stride float4 loads, no tail, no boundary
// branches. Pool strides are ≡ 0 (mod 5) -> constant phase per thread.
#define NB0 1600
#define NB1 400
#define NB2 100
#define NB_SCAN (NB0 + NB1 + NB2)     // 2100
#define NB_CORR ((BT + 255) / 256)    // 15
#define NB_ALL (NB_SCAN + NB_CORR)    // 2115
#define POOL0 (NB0 * 256)             // 409600 float4s (= 6144000/15)
#define POOL1 (NB1 * 256)             // 102400
#define POOL2 (NB2 * 256)             // 25600
#define N_TOTAL 6451200.0f            // 64*3*(160^2+80^2+40^2)

__device__ __forceinline__ float softplus_f(float x) {
    // stable softplus with fast hw transcendentals; abs err < 1e-6
    float e = __expf(-fabsf(x));
    return fmaxf(x, 0.0f) + __logf(1.0f + e);
}

__device__ __forceinline__ float pick(float4 f, int ph) {
    // ph in 1..4 -> component ph-1 (caller gates ph==0)
    return (ph == 1) ? f.x : (ph == 2) ? f.y : (ph == 3) ? f.z : f.w;
}

__device__ __forceinline__ float block_reduce_sum(float v) {
    for (int o = 32; o > 0; o >>= 1) v += __shfl_down(v, o, 64);
    __shared__ float s[4];
    int lane = threadIdx.x & 63;
    int w = threadIdx.x >> 6;
    if (lane == 0) s[w] = v;
    __syncthreads();
    if (threadIdx.x == 0) {
        float t = 0.0f;
        #pragma unroll
        for (int i = 0; i < 4; ++i) t += s[i];
        return t;
    }
    return 0.0f;
}

// Exactly 15 unconditional, uniform-base, coalesced float4 loads per thread.
// phase = g0 % 5 is INVARIANT across iterations (stride ≡ 0 mod 5); lanes
// with phase==0 carry no logit and skip entirely (their lines are fetched
// by neighboring lanes anyway).
__device__ __forceinline__ float scan15(const float4* __restrict__ p,
                                        int g0, int stride) {
    float acc = 0.0f;
    int phase = g0 % 5;
    if (phase) {
        #pragma unroll
        for (int grp = 0; grp < 3; ++grp) {
            int base = g0 + (5 * grp) * stride;
            float4 f0 = p[base];
            float4 f1 = p[base + stride];
            float4 f2 = p[base + 2 * stride];
            float4 f3 = p[base + 3 * stride];
            float4 f4 = p[base + 4 * stride];
            acc += softplus_f(pick(f0, phase));
            acc += softplus_f(pick(f1, phase));
            acc += softplus_f(pick(f2, phase));
            acc += softplus_f(pick(f3, phase));
            acc += softplus_f(pick(f4, phase));
        }
    }
    return acc;
}

// ---------------------------------------------------------------------------
// Main kernel. Block roles:
//   [0,1600)      : scan det0      [1600,2000): scan det1
//   [2000,2100)   : scan det2      [2100,2115): sparse correction
// Correction: y in {1,-1,0}; delta = -y*x - 0.5*y*softplus(-x)
// ---------------------------------------------------------------------------
__global__ void __launch_bounds__(256, 8) fused_main_kernel(
    const float* __restrict__ d0f, const float* __restrict__ d1f,
    const float* __restrict__ d2f, const float* __restrict__ anchors,
    const float* __restrict__ targets, float* __restrict__ partials) {
    float acc = 0.0f;

    if (blockIdx.x < NB0) {
        int g0 = blockIdx.x * 256 + threadIdx.x;
        acc = scan15((const float4*)d0f, g0, POOL0);
    } else if (blockIdx.x < NB0 + NB1) {
        int g0 = (blockIdx.x - NB0) * 256 + threadIdx.x;
        acc = scan15((const float4*)d1f, g0, POOL1);
    } else if (blockIdx.x < NB_SCAN) {
        int g0 = (blockIdx.x - NB0 - NB1) * 256 + threadIdx.x;
        acc = scan15((const float4*)d2f, g0, POOL2);
    } else {
        int tid = (blockIdx.x - NB_SCAN) * 256 + threadIdx.x;
        if (tid < BT) {
            int bi = tid / T;
            const float* tg = targets + tid * 4;
            float tx = tg[0], ty = tg[1], tw = tg[2], th = tg[3];
            bool mask = (tx != -1.0f) && (ty != -1.0f) &&
                        (tw != -1.0f) && (th != -1.0f);
            const int dims[NS] = {160, 80, 40};
            const float* dets[NS] = {d0f, d1f, d2f};

            float ov[NS][NA];
            float mx = -INFINITY;
            #pragma unroll
            for (int si = 0; si < NS; ++si) {
                float D = (float)dims[si];     // H == W at every scale
                float ztx = tx * D, zty = ty * D, ztw = tw * D, zth = th * D;
                float fx = ztx - (floorf(ztx) + 0.5f);
                float fy = zty - (floorf(zty) + 0.5f);
                float tarea = (ztw - fx) * (zth - fy);  // reference's exact expr
                #pragma unroll
                for (int ai = 0; ai < NA; ++ai) {
                    float a0 = anchors[(si * NA + ai) * 2 + 0];
                    float a1 = anchors[(si * NA + ai) * 2 + 1];
                    float lb0 = fmaxf(-0.5f * a0, fx - 0.5f * ztw);
                    float ub0 = fminf( 0.5f * a0, fx + 0.5f * ztw);
                    float lb1 = fmaxf(-0.5f * a1, fy - 0.5f * zth);
                    float ub1 = fminf( 0.5f * a1, fy + 0.5f * zth);
                    float m = ((lb0 < ub0) && (lb1 < ub1)) ? 1.0f : 0.0f;
                    float inter = (ub0 - lb0) * (ub1 - lb1) * m;
                    float v = inter / (a0 * a1 + tarea - inter);
                    ov[si][ai] = v;
                    mx = fmaxf(mx, v);
                }
            }
            if (mask) {
                #pragma unroll
                for (int si = 0; si < NS; ++si) {
                    int D = dims[si];
                    int cy = (int)(ty * (float)D);
                    int cx = (int)(tx * (float)D);
                    if (cy >= 0 && cy < D && cx >= 0 && cx < D) {
                        #pragma unroll
                        for (int ai = 0; ai < NA; ++ai) {
                            float v = ov[si][ai];
                            float y = (v == mx) ? 1.0f
                                    : ((v < 0.5f) ? 0.0f : -1.0f);
                            if (y != 0.0f) {
                                long idx = ((((long)bi * NA + ai) * D + cy) * D + cx) * 5 + 4;
                                float x = dets[si][idx];
                                acc += -y * x - 0.5f * y * softplus_f(-x);
                            }
                        }
                    }
                }
            }
        }
    }

    float bs = block_reduce_sum(acc);
    if (threadIdx.x == 0) partials[blockIdx.x] = bs;
}

// ---------------------------------------------------------------------------
// Final deterministic reduce of all 2115 block partials -> mean.
// ---------------------------------------------------------------------------
__global__ void __launch_bounds__(256) final_kernel(
    const float* __restrict__ wsf, float* __restrict__ out) {
    float acc = 0.0f;
    for (int i = threadIdx.x; i < NB_ALL; i += blockDim.x)
        acc += wsf[i];
    float bs = block_reduce_sum(acc);
    if (threadIdx.x == 0) out[0] = bs / N_TOTAL;
}

extern "C" void kernel_launch(void* const* d_in, const int* in_sizes, int n_in,
                              void* d_out, int out_size, void* d_ws, size_t ws_size,
                              hipStream_t stream) {
    const float* det0    = (const float*)d_in[0];
    const float* det1    = (const float*)d_in[1];
    const float* det2    = (const float*)d_in[2];
    const float* anchors = (const float*)d_in[3];
    const float* targets = (const float*)d_in[4];
    float* out = (float*)d_out;
    float* wsf = (float*)d_ws;

    fused_main_kernel<<<NB_ALL, 256, 0, stream>>>(det0, det1, det2,
                                                  anchors, targets, wsf);
    final_kernel<<<1, 256, 0, stream>>>(wsf, out);
}

// Round 7
// 28.771 us; speedup vs baseline: 3.2436x; 1.0721x over previous
//
#include <hip/hip_runtime.h>
#include <math.h>

// Problem constants (fixed by setup_inputs)
#define B 64
#define T 60
#define NA 3
#define NS 3
#define BT (B*T)

#define NB_SCAN 2048
#define NB_CORR ((BT + 255) / 256)    // 15
#define NB_ALL (NB_SCAN + NB_CORR)    // 2063
#define NT 524288                     // scan threads; NT % 5 == 3
#define N_TOTAL 6451200.0f

// Flattened det space: 8064000 float4s. Chunk = 256 float4s.
// Tensor boundaries at chunk 24000 (det0/det1) and 30000 (det1/det2) are
// block-uniform because chunk(b,k) = b + 2048*k.
#define CH_B1 24000u
#define CH_B2 30000u
#define OFF_D1 6144000
#define OFF_D2 7680000
#define NB_16TH 780                   // blocks doing the 16th load (all det2)

typedef float float4n __attribute__((ext_vector_type(4)));

__device__ __forceinline__ float softplus_f(float x) {
    // stable softplus with fast hw transcendentals; abs err < 1e-6
    float e = __expf(-fabsf(x));
    return fmaxf(x, 0.0f) + __logf(1.0f + e);
}

__device__ __forceinline__ float pickn(float4n f, int ph) {
    // ph in 1..4 -> component ph-1 (caller gates ph==0)
    return (ph == 1) ? f[0] : (ph == 2) ? f[1] : (ph == 3) ? f[2] : f[3];
}

__device__ __forceinline__ float block_reduce_sum(float v) {
    for (int o = 32; o > 0; o >>= 1) v += __shfl_down(v, o, 64);
    __shared__ float s[4];
    int lane = threadIdx.x & 63;
    int w = threadIdx.x >> 6;
    if (lane == 0) s[w] = v;
    __syncthreads();
    if (threadIdx.x == 0) {
        float t = 0.0f;
        #pragma unroll
        for (int i = 0; i < 4; ++i) t += s[i];
        return t;
    }
    return 0.0f;
}

// ---------------------------------------------------------------------------
// Main kernel. Block roles:
//   [0,2048)    : streaming softplus sum over flattened det space
//   [2048,2063) : sparse correction, delta = -y*x - 0.5*y*softplus(-x)
// ---------------------------------------------------------------------------
__global__ void __launch_bounds__(256, 8) fused_main_kernel(
    const float* __restrict__ d0f, const float* __restrict__ d1f,
    const float* __restrict__ d2f, const float* __restrict__ anchors,
    const float* __restrict__ targets, float* __restrict__ partials) {
    float acc = 0.0f;

    if (blockIdx.x < NB_SCAN) {
        int g0 = blockIdx.x * 256 + threadIdx.x;
        int p0 = g0 % 5;
        // 3 groups of 5 batched NT loads; tensor select is a block-uniform
        // branchless pointer select (no control flow between loads).
        #pragma unroll
        for (int grp = 0; grp < 3; ++grp) {
            float4n f0, f1, f2, f3, f4;
            #define LOADJ(J, DEST)                                           \
            {                                                                \
                const int k = grp * 5 + (J);                                 \
                const int idx = g0 + k * NT;                                 \
                const unsigned chunk = blockIdx.x + (unsigned)k * 2048u;     \
                const float* bp = (chunk < CH_B1) ? d0f                      \
                                : (chunk < CH_B2) ? d1f : d2f;               \
                const int off = (chunk < CH_B1) ? idx                        \
                              : (chunk < CH_B2) ? (idx - OFF_D1)             \
                                                : (idx - OFF_D2);            \
                DEST = __builtin_nontemporal_load((const float4n*)bp + off); \
            }
            LOADJ(0, f0) LOADJ(1, f1) LOADJ(2, f2) LOADJ(3, f3) LOADJ(4, f4)
            #undef LOADJ
            // phase for load k: (p0 + 3k) mod 5 — every thread hits phase 0
            // exactly once per group of 5.
            #define EATJ(J, SRC)                                             \
            {                                                                \
                const int c = (3 * (grp * 5 + (J))) % 5;                     \
                int ph = p0 + c; if (ph >= 5) ph -= 5;                       \
                if (ph) acc += softplus_f(pickn(SRC, ph));                   \
            }
            EATJ(0, f0) EATJ(1, f1) EATJ(2, f2) EATJ(3, f3) EATJ(4, f4)
            #undef EATJ
        }
        if (blockIdx.x < NB_16TH) {    // uniform 16th load, always det2
            int idx = g0 + 15 * NT;
            float4n f = __builtin_nontemporal_load(
                (const float4n*)d2f + (idx - OFF_D2));
            if (p0) acc += softplus_f(pickn(f, p0)); // phase = (p0+45)%5 = p0
        }
    } else {
        int tid = (blockIdx.x - NB_SCAN) * 256 + threadIdx.x;
        if (tid < BT) {
            int bi = tid / T;
            const float* tg = targets + tid * 4;
            float tx = tg[0], ty = tg[1], tw = tg[2], th = tg[3];
            bool mask = (tx != -1.0f) && (ty != -1.0f) &&
                        (tw != -1.0f) && (th != -1.0f);
            const int dims[NS] = {160, 80, 40};
            const float* dets[NS] = {d0f, d1f, d2f};

            float ov[NS][NA];
            float mx = -INFINITY;
            #pragma unroll
            for (int si = 0; si < NS; ++si) {
                float D = (float)dims[si];     // H == W at every scale
                float ztx = tx * D, zty = ty * D, ztw = tw * D, zth = th * D;
                float fx = ztx - (floorf(ztx) + 0.5f);
                float fy = zty - (floorf(zty) + 0.5f);
                float tarea = (ztw - fx) * (zth - fy);  // reference's exact expr
                #pragma unroll
                for (int ai = 0; ai < NA; ++ai) {
                    float a0 = anchors[(si * NA + ai) * 2 + 0];
                    float a1 = anchors[(si * NA + ai) * 2 + 1];
                    float lb0 = fmaxf(-0.5f * a0, fx - 0.5f * ztw);
                    float ub0 = fminf( 0.5f * a0, fx + 0.5f * ztw);
                    float lb1 = fmaxf(-0.5f * a1, fy - 0.5f * zth);
                    float ub1 = fminf( 0.5f * a1, fy + 0.5f * zth);
                    float m = ((lb0 < ub0) && (lb1 < ub1)) ? 1.0f : 0.0f;
                    float inter = (ub0 - lb0) * (ub1 - lb1) * m;
                    float v = inter / (a0 * a1 + tarea - inter);
                    ov[si][ai] = v;
                    mx = fmaxf(mx, v);
                }
            }
            if (mask) {
                #pragma unroll
                for (int si = 0; si < NS; ++si) {
                    int D = dims[si];
                    int cy = (int)(ty * (float)D);
                    int cx = (int)(tx * (float)D);
                    if (cy >= 0 && cy < D && cx >= 0 && cx < D) {
                        #pragma unroll
                        for (int ai = 0; ai < NA; ++ai) {
                            float v = ov[si][ai];
                            float y = (v == mx) ? 1.0f
                                    : ((v < 0.5f) ? 0.0f : -1.0f);
                            if (y != 0.0f) {
                                long idx = ((((long)bi * NA + ai) * D + cy) * D + cx) * 5 + 4;
                                float x = dets[si][idx];
                                acc += -y * x - 0.5f * y * softplus_f(-x);
                            }
                        }
                    }
                }
            }
        }
    }

    float bs = block_reduce_sum(acc);
    if (threadIdx.x == 0) partials[blockIdx.x] = bs;
}

// ---------------------------------------------------------------------------
// Final deterministic reduce of all 2063 block partials -> mean.
// ---------------------------------------------------------------------------
__global__ void __launch_bounds__(256) final_kernel(
    const float* __restrict__ wsf, float* __restrict__ out) {
    float acc = 0.0f;
    for (int i = threadIdx.x; i < NB_ALL; i += blockDim.x)
        acc += wsf[i];
    float bs = block_reduce_sum(acc);
    if (threadIdx.x == 0) out[0] = bs / N_TOTAL;
}

extern "C" void kernel_launch(void* const* d_in, const int* in_sizes, int n_in,
                              void* d_out, int out_size, void* d_ws, size_t ws_size,
                              hipStream_t stream) {
    const float* det0    = (const float*)d_in[0];
    const float* det1    = (const float*)d_in[1];
    const float* det2    = (const float*)d_in[2];
    const float* anchors = (const float*)d_in[3];
    const float* targets = (const float*)d_in[4];
    float* out = (float*)d_out;
    float* wsf = (float*)d_ws;

    fused_main_kernel<<<NB_ALL, 256, 0, stream>>>(det0, det1, det2,
                                                  anchors, targets, wsf);
    final_kernel<<<1, 256, 0, stream>>>(wsf, out);
}